// Round 1
// baseline (369.989 us; speedup 1.0000x reference)
//
#include <hip/hip_runtime.h>
#include <cstdint>

typedef unsigned short u16;
typedef __attribute__((ext_vector_type(8))) __bf16 bf16x8;
typedef __attribute__((ext_vector_type(4))) float f32x4;
typedef __attribute__((ext_vector_type(8))) unsigned short u16x8;

#define DEV __device__ __forceinline__

DEV u16 f2bf(float f) {
  unsigned u = __float_as_uint(f);
  return (u16)((u + 0x7FFFu + ((u >> 16) & 1u)) >> 16);
}
DEV float bf2f(u16 h) { return __uint_as_float(((unsigned)h) << 16); }

typedef __attribute__((address_space(1))) void gvoid_t;
typedef __attribute__((address_space(3))) void lvoid_t;

DEV void gload_lds16(const void* g, void* l) {
  __builtin_amdgcn_global_load_lds((gvoid_t*)(void*)(uintptr_t)g,
                                   (lvoid_t*)l, 16, 0, 0);
}

// ---- problem sizes
#define B_   2
#define T_   2048
#define DM   2048
#define DHD  128
#define MROWS (B_*T_)   // 4096
#define DKV  512

// ---------- x f32 -> bf16 ----------
__global__ void k_convert(const float* __restrict__ in, u16* __restrict__ out, int n4) {
  int i = blockIdx.x * blockDim.x + threadIdx.x;
  if (i >= n4) return;
  float4 v = ((const float4*)in)[i];
  ((ushort4*)out)[i] = make_ushort4(f2bf(v.x), f2bf(v.y), f2bf(v.z), f2bf(v.w));
}

// ---------- weight f32 [R][C] -> bf16 [C][R] ----------
__global__ void k_transpose(const float* __restrict__ in, u16* __restrict__ out, int R, int C) {
  __shared__ float tile[32][33];
  int c0 = blockIdx.x * 32, r0 = blockIdx.y * 32;
  int tx = threadIdx.x, ty = threadIdx.y;   // (32, 8)
  #pragma unroll
  for (int j = 0; j < 32; j += 8)
    tile[ty + j][tx] = in[(size_t)(r0 + ty + j) * C + c0 + tx];
  __syncthreads();
  #pragma unroll
  for (int j = 0; j < 32; j += 8)
    out[(size_t)(c0 + ty + j) * R + r0 + tx] = f2bf(tile[tx][ty + j]);
}

// ---------- RoPE cos/sin table [T][64] ----------
__global__ void k_rope_table(float2* __restrict__ tab) {
  int i = blockIdx.x * blockDim.x + threadIdx.x;   // < 2048*64
  int pos = i >> 6, d = i & 63;
  float ang = powf(10000.0f, -(float)d / 64.0f);
  float s, c;
  sincosf((float)pos * ang, &s, &c);
  tab[i] = make_float2(c, s);
}

// ---------- bf16 GEMM: C[M][N] = A[M][K] * BT[N][K]^T ----------
template <typename OutT>
__global__ __launch_bounds__(256) void k_gemm(
    const u16* __restrict__ A, const u16* __restrict__ BT, OutT* __restrict__ C,
    int M, int N, int K) {
  __shared__ u16 As[128 * 64];
  __shared__ u16 Bs[128 * 64];
  const int tid = threadIdx.x;
  const int w = tid >> 6, lane = tid & 63;
  const int lr = lane & 15, lg = lane >> 4;
  const int m0 = blockIdx.y * 128, n0 = blockIdx.x * 128;
  const int wr = w >> 1, wc = w & 1;
  f32x4 acc[4][4] = {};
  for (int k0 = 0; k0 < K; k0 += 64) {
    __syncthreads();
    #pragma unroll
    for (int i = 0; i < 4; i++) {
      int idx = i * 256 + tid;            // 0..1023
      int row = idx >> 3, blk = idx & 7;  // 8x16B blocks per 128B row
      int scol = ((blk ^ (row & 7)) << 3);
      gload_lds16(&A[(size_t)(m0 + row) * K + k0 + scol], &As[(idx & ~63) * 8]);
      gload_lds16(&BT[(size_t)(n0 + row) * K + k0 + scol], &Bs[(idx & ~63) * 8]);
    }
    __syncthreads();
    #pragma unroll
    for (int kk = 0; kk < 2; kk++) {
      bf16x8 af[4], bfr[4];
      #pragma unroll
      for (int m = 0; m < 4; m++) {
        int row = wr * 64 + m * 16 + lr;
        af[m] = *(const bf16x8*)&As[row * 64 + (((kk * 4 + lg) ^ (lr & 7)) << 3)];
      }
      #pragma unroll
      for (int n = 0; n < 4; n++) {
        int row = wc * 64 + n * 16 + lr;
        bfr[n] = *(const bf16x8*)&Bs[row * 64 + (((kk * 4 + lg) ^ (lr & 7)) << 3)];
      }
      #pragma unroll
      for (int m = 0; m < 4; m++)
        #pragma unroll
        for (int n = 0; n < 4; n++)
          acc[m][n] = __builtin_amdgcn_mfma_f32_16x16x32_bf16(af[m], bfr[n], acc[m][n], 0, 0, 0);
    }
  }
  #pragma unroll
  for (int m = 0; m < 4; m++)
    #pragma unroll
    for (int n = 0; n < 4; n++)
      #pragma unroll
      for (int r = 0; r < 4; r++) {
        int row = m0 + wr * 64 + m * 16 + lg * 4 + r;
        int col = n0 + wc * 64 + n * 16 + lr;
        if constexpr (sizeof(OutT) == 2) C[(size_t)row * N + col] = f2bf(acc[m][n][r]);
        else                             C[(size_t)row * N + col] = acc[m][n][r];
      }
}

// ---------- Q: RMSNorm * gq, RoPE, * D^-0.5 ; [bt][2048] -> [b,g,h,t,d] ----------
__global__ void k_norm_rope_q(const u16* __restrict__ qf, const float* __restrict__ gq,
                              const float2* __restrict__ tab, u16* __restrict__ qb) {
  int w = threadIdx.x >> 6, lane = threadIdx.x & 63;
  int W = blockIdx.x * 4 + w;               // 0..65535
  int h = W & 3, g = (W >> 2) & 3;
  int bt = W >> 4;
  int t = bt & 2047, b = bt >> 11;
  const u16* row = qf + (size_t)bt * DM + (size_t)(g * 4 + h) * 128;
  float v0 = bf2f(row[lane]);
  float v1 = bf2f(row[lane + 64]);
  float ss = v0 * v0 + v1 * v1;
  #pragma unroll
  for (int off = 1; off < 64; off <<= 1) ss += __shfl_xor(ss, off, 64);
  float inv = 1.0f / sqrtf(ss * (1.0f / 128.0f) + 1e-6f);
  v0 *= inv * gq[(g * 4 + h) * 128 + lane];
  v1 *= inv * gq[(g * 4 + h) * 128 + 64 + lane];
  float2 cs = tab[t * 64 + lane];
  const float sc = 0.08838834764831845f;    // 128^-0.5 (both mult factors folded)
  float o0 = (v0 * cs.x - v1 * cs.y) * sc;
  float o1 = (v0 * cs.y + v1 * cs.x) * sc;
  u16* orow = qb + ((size_t)(((b * 4 + g) * 4 + h) * 2048 + t)) * 128;
  orow[lane] = f2bf(o0);
  orow[lane + 64] = f2bf(o1);
}

// ---------- K: RMSNorm * gk, RoPE ; [bt][512] -> [b,g,t,d] ----------
__global__ void k_norm_rope_k(const u16* __restrict__ kf, const float* __restrict__ gk,
                              const float2* __restrict__ tab, u16* __restrict__ kb) {
  int w = threadIdx.x >> 6, lane = threadIdx.x & 63;
  int W = blockIdx.x * 4 + w;               // 0..16383
  int g = W & 3;
  int bt = W >> 2;
  int t = bt & 2047, b = bt >> 11;
  const u16* row = kf + (size_t)bt * DKV + (size_t)g * 128;
  float v0 = bf2f(row[lane]);
  float v1 = bf2f(row[lane + 64]);
  float ss = v0 * v0 + v1 * v1;
  #pragma unroll
  for (int off = 1; off < 64; off <<= 1) ss += __shfl_xor(ss, off, 64);
  float inv = 1.0f / sqrtf(ss * (1.0f / 128.0f) + 1e-6f);
  v0 *= inv * gk[g * 128 + lane];
  v1 *= inv * gk[g * 128 + 64 + lane];
  float2 cs = tab[t * 64 + lane];
  float o0 = v0 * cs.x - v1 * cs.y;
  float o1 = v0 * cs.y + v1 * cs.x;
  u16* orow = kb + ((size_t)((b * 4 + g) * 2048 + t)) * 128;
  orow[lane] = f2bf(o0);
  orow[lane + 64] = f2bf(o1);
}

// ---------- V: [bt][512] -> VT [b,g,d,t] ----------
__global__ void k_pack_vt(const u16* __restrict__ vf, u16* __restrict__ vt) {
  int w = threadIdx.x >> 6, lane = threadIdx.x & 63;
  int W = blockIdx.x * 4 + w;               // 0..4095
  int t8 = W & 255, dh = (W >> 8) & 1, bg = W >> 9;
  int b = bg >> 2, g = bg & 3;
  int t0 = t8 * 8;
  int d = dh * 64 + lane;
  u16x8 pack;
  #pragma unroll
  for (int j = 0; j < 8; j++)
    pack[j] = vf[(size_t)(b * 2048 + t0 + j) * DKV + g * 128 + d];
  *(u16x8*)&vt[((size_t)(bg * 128 + d)) * 2048 + t0] = pack;
}

// ---------- causal flash attention ----------
__global__ __launch_bounds__(256) void k_attn(
    const u16* __restrict__ qb, const u16* __restrict__ kb,
    const u16* __restrict__ vtb, u16* __restrict__ ob) {
  __shared__ u16 Ks[64 * 128];       // [kv][d], 16B-block XOR-swizzled
  __shared__ u16 Vs[128 * 64];       // [d][kv], swizzled
  __shared__ u16 Ps[4][16 * 64];     // per-wave P strip, swizzled
  const int head = blockIdx.y;       // ((b*4+g)*4+h)
  const int qblk = blockIdx.x;
  const int b = head >> 4;
  const int g = (head >> 2) & 3;
  const int h = head & 3;
  const int tid = threadIdx.x;
  const int w = tid >> 6, lane = tid & 63;
  const int lr = lane & 15, lg = lane >> 4;
  const int q0 = qblk * 64;
  const u16* qh = qb + (size_t)head * (T_ * 128);
  const u16* kh = kb + (size_t)(b * 4 + g) * (T_ * 128);
  const u16* vh = vtb + (size_t)(b * 4 + g) * (128 * T_);

  bf16x8 qf[4];
  const int qrow = q0 + w * 16 + lr;
  #pragma unroll
  for (int kk = 0; kk < 4; kk++)
    qf[kk] = *(const bf16x8*)&qh[(size_t)qrow * 128 + kk * 32 + lg * 8];

  f32x4 oacc[8] = {};
  float mrun[4], lrun[4];
  #pragma unroll
  for (int r = 0; r < 4; r++) { mrun[r] = -3.0e38f; lrun[r] = 0.f; }

  for (int jt = 0; jt <= qblk; ++jt) {
    const int j0 = jt * 64;
    __syncthreads();
    #pragma unroll
    for (int i = 0; i < 4; i++) {                   // K tile: 64x128
      int idx = i * 256 + tid;
      int row = idx >> 4, blk = idx & 15;
      gload_lds16(&kh[(size_t)(j0 + row) * 128 + ((blk ^ (row & 7)) << 3)],
                  &Ks[(idx & ~63) * 8]);
    }
    #pragma unroll
    for (int i = 0; i < 4; i++) {                   // VT tile: 128 x 64
      int idx = i * 256 + tid;
      int row = idx >> 3, blk = idx & 7;
      gload_lds16(&vh[(size_t)row * T_ + j0 + ((blk ^ (row & 7)) << 3)],
                  &Vs[(idx & ~63) * 8]);
    }
    __syncthreads();

    // S = Q K^T  (16 q-rows per wave x 64 kv)
    f32x4 s[4];
    #pragma unroll
    for (int c = 0; c < 4; c++) {
      s[c] = (f32x4){0.f, 0.f, 0.f, 0.f};
      const int kvr = c * 16 + lr;
      #pragma unroll
      for (int kk = 0; kk < 4; kk++) {
        bf16x8 kf = *(const bf16x8*)&Ks[kvr * 128 + (((kk * 4 + lg) ^ (kvr & 7)) << 3)];
        s[c] = __builtin_amdgcn_mfma_f32_16x16x32_bf16(qf[kk], kf, s[c], 0, 0, 0);
      }
    }
    if (j0 == q0) {                                 // causal mask on diagonal tile
      #pragma unroll
      for (int c = 0; c < 4; c++)
        #pragma unroll
        for (int r = 0; r < 4; r++)
          if (c * 16 + lr > w * 16 + lg * 4 + r) s[c][r] = -3.0e38f;
    }
    // online softmax, wave-parallel
    #pragma unroll
    for (int r = 0; r < 4; r++) {
      float mx = fmaxf(fmaxf(s[0][r], s[1][r]), fmaxf(s[2][r], s[3][r]));
      mx = fmaxf(mx, __shfl_xor(mx, 1, 64));
      mx = fmaxf(mx, __shfl_xor(mx, 2, 64));
      mx = fmaxf(mx, __shfl_xor(mx, 4, 64));
      mx = fmaxf(mx, __shfl_xor(mx, 8, 64));
      float mnew = fmaxf(mrun[r], mx);
      float corr = __expf(mrun[r] - mnew);
      mrun[r] = mnew;
      float rs = 0.f;
      #pragma unroll
      for (int c = 0; c < 4; c++) {
        float pv = __expf(s[c][r] - mnew);
        s[c][r] = pv;
        rs += pv;
      }
      rs += __shfl_xor(rs, 1, 64);
      rs += __shfl_xor(rs, 2, 64);
      rs += __shfl_xor(rs, 4, 64);
      rs += __shfl_xor(rs, 8, 64);
      lrun[r] = lrun[r] * corr + rs;
      #pragma unroll
      for (int nd = 0; nd < 8; nd++) oacc[nd][r] *= corr;
    }
    // P -> LDS (per-wave strip, swizzled rows of 128B)
    #pragma unroll
    for (int c = 0; c < 4; c++)
      #pragma unroll
      for (int r = 0; r < 4; r++) {
        int qr = lg * 4 + r;
        int kv = c * 16 + lr;
        Ps[w][qr * 64 + (((kv >> 3) ^ (qr & 7)) << 3) + (kv & 7)] = f2bf(s[c][r]);
      }
    // O += P V
    #pragma unroll
    for (int ks = 0; ks < 2; ks++) {
      bf16x8 pf = *(const bf16x8*)&Ps[w][lr * 64 + (((ks * 4 + lg) ^ (lr & 7)) << 3)];
      #pragma unroll
      for (int nd = 0; nd < 8; nd++) {
        const int d = nd * 16 + lr;
        bf16x8 vf = *(const bf16x8*)&Vs[d * 64 + (((ks * 4 + lg) ^ (d & 7)) << 3)];
        oacc[nd] = __builtin_amdgcn_mfma_f32_16x16x32_bf16(pf, vf, oacc[nd], 0, 0, 0);
      }
    }
  }
  // epilogue: normalize and write [bt][2048]
  #pragma unroll
  for (int r = 0; r < 4; r++) {
    float inv = 1.0f / lrun[r];
    int orow = q0 + w * 16 + lg * 4 + r;
    size_t base = (size_t)(b * T_ + orow) * 2048 + (size_t)(g * 4 + h) * 128;
    #pragma unroll
    for (int nd = 0; nd < 8; nd++)
      ob[base + nd * 16 + lr] = f2bf(oacc[nd][r] * inv);
  }
}

// ---------- workspace layout (bytes) ----------
#define OFF_XB   ((size_t)0)
#define OFF_WQT  ((size_t)16777216)
#define OFF_WKT  ((size_t)25165824)
#define OFF_WVT  ((size_t)27262976)
#define OFF_WOT  ((size_t)29360128)
#define OFF_ROPE ((size_t)37748736)
#define OFF_QB   ((size_t)38797312)
#define OFF_KB   ((size_t)55574528)
#define OFF_VTB  ((size_t)59768832)
#define OFF_QF   ((size_t)63963136)
#define OFF_KF   ((size_t)80740352)
#define OFF_VF   ((size_t)84934656)
#define OFF_OB   OFF_QF   /* reuse: q_bf dead once norm_rope_q has run */

extern "C" void kernel_launch(void* const* d_in, const int* in_sizes, int n_in,
                              void* d_out, int out_size, void* d_ws, size_t ws_size,
                              hipStream_t stream) {
  const float* x  = (const float*)d_in[0];
  const float* wq = (const float*)d_in[1];
  const float* wk = (const float*)d_in[2];
  const float* wv = (const float*)d_in[3];
  const float* wo = (const float*)d_in[4];
  const float* gq = (const float*)d_in[5];
  const float* gk = (const float*)d_in[6];
  float* out = (float*)d_out;
  char* ws = (char*)d_ws;

  u16*    xb   = (u16*)(ws + OFF_XB);
  u16*    wqt  = (u16*)(ws + OFF_WQT);
  u16*    wkt  = (u16*)(ws + OFF_WKT);
  u16*    wvt  = (u16*)(ws + OFF_WVT);
  u16*    wot  = (u16*)(ws + OFF_WOT);
  float2* rope = (float2*)(ws + OFF_ROPE);
  u16*    qbuf = (u16*)(ws + OFF_QB);
  u16*    kbuf = (u16*)(ws + OFF_KB);
  u16*    vtb  = (u16*)(ws + OFF_VTB);
  u16*    q_bf = (u16*)(ws + OFF_QF);
  u16*    k_bf = (u16*)(ws + OFF_KF);
  u16*    v_bf = (u16*)(ws + OFF_VF);
  u16*    obuf = (u16*)(ws + OFF_OB);

  // 1. conversions
  k_convert<<<8192, 256, 0, stream>>>(x, xb, (MROWS * DM) / 4);
  k_transpose<<<dim3(64, 64), dim3(32, 8), 0, stream>>>(wq, wqt, 2048, 2048);
  k_transpose<<<dim3(16, 64), dim3(32, 8), 0, stream>>>(wk, wkt, 2048, 512);
  k_transpose<<<dim3(16, 64), dim3(32, 8), 0, stream>>>(wv, wvt, 2048, 512);
  k_transpose<<<dim3(64, 64), dim3(32, 8), 0, stream>>>(wo, wot, 2048, 2048);
  k_rope_table<<<512, 256, 0, stream>>>(rope);
  // 2. projections (bf16 out)
  k_gemm<u16><<<dim3(16, 32), 256, 0, stream>>>(xb, wqt, q_bf, MROWS, 2048, 2048);
  k_gemm<u16><<<dim3(4, 32), 256, 0, stream>>>(xb, wkt, k_bf, MROWS, 512, 2048);
  k_gemm<u16><<<dim3(4, 32), 256, 0, stream>>>(xb, wvt, v_bf, MROWS, 512, 2048);
  // 3. norm + rope + layout
  k_norm_rope_q<<<16384, 256, 0, stream>>>(q_bf, gq, rope, qbuf);
  k_norm_rope_k<<<4096, 256, 0, stream>>>(k_bf, gk, rope, kbuf);
  k_pack_vt<<<1024, 256, 0, stream>>>(v_bf, vtb);
  // 4. attention (writes obuf, aliases q_bf which is now dead)
  k_attn<<<dim3(32, 32), 256, 0, stream>>>(qbuf, kbuf, vtb, obuf);
  // 5. output projection (fp32 out)
  k_gemm<float><<<dim3(16, 32), 256, 0, stream>>>(obuf, wot, out, MROWS, 2048, 2048);
}

// Round 2
// 249.382 us; speedup vs baseline: 1.4836x; 1.4836x over previous
//
#include <hip/hip_runtime.h>
#include <cstdint>

typedef unsigned short u16;
typedef __attribute__((ext_vector_type(8))) __bf16 bf16x8;
typedef __attribute__((ext_vector_type(4))) float f32x4;
typedef __attribute__((ext_vector_type(8))) unsigned short u16x8;

#define DEV __device__ __forceinline__

DEV u16 f2bf(float f) {
  unsigned u = __float_as_uint(f);
  return (u16)((u + 0x7FFFu + ((u >> 16) & 1u)) >> 16);
}
DEV float bf2f(u16 h) { return __uint_as_float(((unsigned)h) << 16); }

typedef __attribute__((address_space(1))) void gvoid_t;
typedef __attribute__((address_space(3))) void lvoid_t;

DEV void gload_lds16(const void* g, void* l) {
  __builtin_amdgcn_global_load_lds((gvoid_t*)(void*)(uintptr_t)g,
                                   (lvoid_t*)l, 16, 0, 0);
}

// ---- problem sizes
#define B_   2
#define T_   2048
#define DM   2048
#define MROWS (B_*T_)   // 4096

// ---------- x f32 -> bf16 ----------
__global__ void k_convert(const float* __restrict__ in, u16* __restrict__ out, int n4) {
  int i = blockIdx.x * blockDim.x + threadIdx.x;
  if (i >= n4) return;
  float4 v = ((const float4*)in)[i];
  ((ushort4*)out)[i] = make_ushort4(f2bf(v.x), f2bf(v.y), f2bf(v.z), f2bf(v.w));
}

// ---------- weight f32 [R][C] -> bf16 [C][R] ----------
__global__ void k_transpose(const float* __restrict__ in, u16* __restrict__ out, int R, int C) {
  __shared__ float tile[32][33];
  int c0 = blockIdx.x * 32, r0 = blockIdx.y * 32;
  int tx = threadIdx.x, ty = threadIdx.y;   // (32, 8)
  #pragma unroll
  for (int j = 0; j < 32; j += 8)
    tile[ty + j][tx] = in[(size_t)(r0 + ty + j) * C + c0 + tx];
  __syncthreads();
  #pragma unroll
  for (int j = 0; j < 32; j += 8)
    out[(size_t)(c0 + ty + j) * R + r0 + tx] = f2bf(tile[tx][ty + j]);
}

// ---------- RoPE cos/sin table [T][64] ----------
__global__ void k_rope_table(float2* __restrict__ tab) {
  int i = blockIdx.x * blockDim.x + threadIdx.x;   // < 2048*64
  int pos = i >> 6, d = i & 63;
  float ang = powf(10000.0f, -(float)d / 64.0f);
  float s, c;
  sincosf((float)pos * ang, &s, &c);
  tab[i] = make_float2(c, s);
}

// ---------- bf16 GEMM: C[M][N] = A[M][K] * BT[N][K]^T ----------
template <typename OutT>
__global__ __launch_bounds__(256) void k_gemm(
    const u16* __restrict__ A, const u16* __restrict__ BT, OutT* __restrict__ C,
    int M, int N, int K) {
  __shared__ u16 As[128 * 64];
  __shared__ u16 Bs[128 * 64];
  const int tid = threadIdx.x;
  const int w = tid >> 6, lane = tid & 63;
  const int lr = lane & 15, lg = lane >> 4;
  const int m0 = blockIdx.y * 128, n0 = blockIdx.x * 128;
  const int wr = w >> 1, wc = w & 1;
  f32x4 acc[4][4] = {};
  for (int k0 = 0; k0 < K; k0 += 64) {
    __syncthreads();
    #pragma unroll
    for (int i = 0; i < 4; i++) {
      int idx = i * 256 + tid;            // 0..1023
      int row = idx >> 3, blk = idx & 7;  // 8x16B blocks per 128B row
      int scol = ((blk ^ (row & 7)) << 3);
      gload_lds16(&A[(size_t)(m0 + row) * K + k0 + scol], &As[(idx & ~63) * 8]);
      gload_lds16(&BT[(size_t)(n0 + row) * K + k0 + scol], &Bs[(idx & ~63) * 8]);
    }
    __syncthreads();
    #pragma unroll
    for (int kk = 0; kk < 2; kk++) {
      bf16x8 af[4], bfr[4];
      #pragma unroll
      for (int m = 0; m < 4; m++) {
        int row = wr * 64 + m * 16 + lr;
        af[m] = *(const bf16x8*)&As[row * 64 + (((kk * 4 + lg) ^ (lr & 7)) << 3)];
      }
      #pragma unroll
      for (int n = 0; n < 4; n++) {
        int row = wc * 64 + n * 16 + lr;
        bfr[n] = *(const bf16x8*)&Bs[row * 64 + (((kk * 4 + lg) ^ (lr & 7)) << 3)];
      }
      #pragma unroll
      for (int m = 0; m < 4; m++)
        #pragma unroll
        for (int n = 0; n < 4; n++)
          acc[m][n] = __builtin_amdgcn_mfma_f32_16x16x32_bf16(af[m], bfr[n], acc[m][n], 0, 0, 0);
    }
  }
  #pragma unroll
  for (int m = 0; m < 4; m++)
    #pragma unroll
    for (int n = 0; n < 4; n++)
      #pragma unroll
      for (int r = 0; r < 4; r++) {
        int row = m0 + wr * 64 + m * 16 + lg * 4 + r;
        int col = n0 + wc * 64 + n * 16 + lr;
        if constexpr (sizeof(OutT) == 2) C[(size_t)row * N + col] = f2bf(acc[m][n][r]);
        else                             C[(size_t)row * N + col] = acc[m][n][r];
      }
}

// ---------- Q: RMSNorm * gq, RoPE, * D^-0.5 ; [bt][2048] -> [b,g,h,t,d] ----------
__global__ void k_norm_rope_q(const u16* __restrict__ qf, const float* __restrict__ gq,
                              const float2* __restrict__ tab, u16* __restrict__ qb) {
  int w = threadIdx.x >> 6, lane = threadIdx.x & 63;
  int W = blockIdx.x * 4 + w;               // 0..65535
  int h = W & 3, g = (W >> 2) & 3;
  int bt = W >> 4;
  int t = bt & 2047, b = bt >> 11;
  const u16* row = qf + (size_t)bt * DM + (size_t)(g * 4 + h) * 128;
  float v0 = bf2f(row[lane]);
  float v1 = bf2f(row[lane + 64]);
  float ss = v0 * v0 + v1 * v1;
  #pragma unroll
  for (int off = 1; off < 64; off <<= 1) ss += __shfl_xor(ss, off, 64);
  float inv = 1.0f / sqrtf(ss * (1.0f / 128.0f) + 1e-6f);
  v0 *= inv * gq[(g * 4 + h) * 128 + lane];
  v1 *= inv * gq[(g * 4 + h) * 128 + 64 + lane];
  float2 cs = tab[t * 64 + lane];
  const float sc = 0.08838834764831845f;    // 128^-0.5 (both mult factors folded)
  float o0 = (v0 * cs.x - v1 * cs.y) * sc;
  float o1 = (v0 * cs.y + v1 * cs.x) * sc;
  u16* orow = qb + ((size_t)(((b * 4 + g) * 4 + h) * 2048 + t)) * 128;
  orow[lane] = f2bf(o0);
  orow[lane + 64] = f2bf(o1);
}

// ---------- K: RMSNorm * gk, RoPE ; kv_bf [bt][1024] cols 0..511 -> [b,g,t,d] ----------
__global__ void k_norm_rope_k(const u16* __restrict__ kvf, const float* __restrict__ gk,
                              const float2* __restrict__ tab, u16* __restrict__ kb) {
  int w = threadIdx.x >> 6, lane = threadIdx.x & 63;
  int W = blockIdx.x * 4 + w;               // 0..16383
  int g = W & 3;
  int bt = W >> 2;
  int t = bt & 2047, b = bt >> 11;
  const u16* row = kvf + (size_t)bt * 1024 + (size_t)g * 128;
  float v0 = bf2f(row[lane]);
  float v1 = bf2f(row[lane + 64]);
  float ss = v0 * v0 + v1 * v1;
  #pragma unroll
  for (int off = 1; off < 64; off <<= 1) ss += __shfl_xor(ss, off, 64);
  float inv = 1.0f / sqrtf(ss * (1.0f / 128.0f) + 1e-6f);
  v0 *= inv * gk[g * 128 + lane];
  v1 *= inv * gk[g * 128 + 64 + lane];
  float2 cs = tab[t * 64 + lane];
  float o0 = v0 * cs.x - v1 * cs.y;
  float o1 = v0 * cs.y + v1 * cs.x;
  u16* orow = kb + ((size_t)((b * 4 + g) * 2048 + t)) * 128;
  orow[lane] = f2bf(o0);
  orow[lane + 64] = f2bf(o1);
}

// ---------- V: kv_bf [bt][1024] cols 512..1023 -> VT [b,g,d,t] ----------
__global__ void k_pack_vt(const u16* __restrict__ kvf, u16* __restrict__ vt) {
  int w = threadIdx.x >> 6, lane = threadIdx.x & 63;
  int W = blockIdx.x * 4 + w;               // 0..4095
  int t8 = W & 255, dh = (W >> 8) & 1, bg = W >> 9;
  int b = bg >> 2, g = bg & 3;
  int t0 = t8 * 8;
  int d = dh * 64 + lane;
  u16x8 pack;
  #pragma unroll
  for (int j = 0; j < 8; j++)
    pack[j] = kvf[(size_t)(b * 2048 + t0 + j) * 1024 + 512 + g * 128 + d];
  *(u16x8*)&vt[((size_t)(bg * 128 + d)) * 2048 + t0] = pack;
}

// ---------- staging: K tile [64][128] + VT tile [128][64], pre-swizzled source ----------
DEV void stage_tiles(const u16* kh, const u16* vh, int j0, u16* Kbuf, u16* Vbuf, int tid) {
  #pragma unroll
  for (int i = 0; i < 4; i++) {
    int idx = i * 256 + tid;
    int row = idx >> 4, blk = idx & 15;   // 16x16B blocks per 256B K row
    gload_lds16(&kh[(size_t)(j0 + row) * 128 + ((blk ^ (row & 7)) << 3)],
                &Kbuf[(idx & ~63) * 8]);
  }
  #pragma unroll
  for (int i = 0; i < 4; i++) {
    int idx = i * 256 + tid;
    int row = idx >> 3, blk = idx & 7;    // 8x16B blocks per 128B VT row
    gload_lds16(&vh[(size_t)row * T_ + j0 + ((blk ^ (row & 7)) << 3)],
                &Vbuf[(idx & ~63) * 8]);
  }
}

// ---------- causal flash attention: paired Q-tiles, 2-phase pipeline, swapped QK ----------
__global__ __launch_bounds__(256) void k_attn(
    const u16* __restrict__ qb, const u16* __restrict__ kb,
    const u16* __restrict__ vtb, u16* __restrict__ ob) {
  __shared__ __align__(16) u16 Ks[2][64 * 128];
  __shared__ __align__(16) u16 Vs[2][128 * 64];
  __shared__ __align__(16) u16 Ps[4][16 * 64];
  const int head = blockIdx.y;       // ((b*4+g)*4+h)
  const int b = head >> 4, g = (head >> 2) & 3, h = head & 3;
  const int tid = threadIdx.x;
  const int w = tid >> 6, lane = tid & 63;
  const int lr = lane & 15, lg = lane >> 4;
  const u16* qh = qb + (size_t)head * (T_ * 128);
  const u16* kh = kb + (size_t)(b * 4 + g) * (T_ * 128);
  const u16* vh = vtb + (size_t)(b * 4 + g) * (128 * T_);

  #pragma unroll 1
  for (int half = 0; half < 2; ++half) {
    const int qblk = half ? (int)blockIdx.x : 31 - (int)blockIdx.x;  // big tile first
    const int q0 = qblk * 64;
    // Q fragments (B-operand): lane holds q-col = q0+w*16+lr, d = kk*32+lg*8..+8
    bf16x8 qf[4];
    const int qrow = q0 + w * 16 + lr;
    #pragma unroll
    for (int kk = 0; kk < 4; kk++)
      qf[kk] = *(const bf16x8*)&qh[(size_t)qrow * 128 + kk * 32 + lg * 8];

    f32x4 oacc[8] = {};
    float mrun = -3.0e38f, lrun = 0.f;

    stage_tiles(kh, vh, 0, Ks[0], Vs[0], tid);
    asm volatile("s_waitcnt vmcnt(0)" ::: "memory");
    __builtin_amdgcn_s_barrier();
    asm volatile("" ::: "memory");
    int cur = 0;
    for (int jt = 0; jt <= qblk; ++jt) {
      if (jt < qblk)
        stage_tiles(kh, vh, (jt + 1) * 64, Ks[cur ^ 1], Vs[cur ^ 1], tid);
      const u16* Kc = Ks[cur];
      const u16* Vc = Vs[cur];
      // S^T = K . Q^T : col = q (lr), row = kv (c*16 + lg*4 + r)
      f32x4 s[4] = {};
      #pragma unroll
      for (int kk = 0; kk < 4; kk++) {
        #pragma unroll
        for (int c = 0; c < 4; c++) {
          const int kvr = c * 16 + lr;
          bf16x8 kf = *(const bf16x8*)&Kc[kvr * 128 + (((kk * 4 + lg) ^ (kvr & 7)) << 3)];
          s[c] = __builtin_amdgcn_mfma_f32_16x16x32_bf16(kf, qf[kk], s[c], 0, 0, 0);
        }
      }
      if (jt == qblk) {                   // causal mask, diagonal tile only
        #pragma unroll
        for (int c = 0; c < 4; c++)
          #pragma unroll
          for (int r = 0; r < 4; r++)
            if (c * 16 + lg * 4 + r > w * 16 + lr) s[c][r] = -1.0e30f;
      }
      // online softmax: each lane owns q-row lr; reduce kv across regs + lg lanes
      float mx = s[0][0];
      #pragma unroll
      for (int c = 0; c < 4; c++)
        #pragma unroll
        for (int r = 0; r < 4; r++) mx = fmaxf(mx, s[c][r]);
      mx = fmaxf(mx, __shfl_xor(mx, 16, 64));
      mx = fmaxf(mx, __shfl_xor(mx, 32, 64));
      float mnew = fmaxf(mrun, mx);
      float corr = __expf(mrun - mnew);
      mrun = mnew;
      float rs = 0.f;
      #pragma unroll
      for (int c = 0; c < 4; c++)
        #pragma unroll
        for (int r = 0; r < 4; r++) {
          float pv = __expf(s[c][r] - mnew);
          s[c][r] = pv;
          rs += pv;
        }
      rs += __shfl_xor(rs, 16, 64);
      rs += __shfl_xor(rs, 32, 64);
      lrun = lrun * corr + rs;
      // P store: P[q=lr][kv quad c*16+lg*4], b64, XOR-swizzled 8B blocks
      #pragma unroll
      for (int c = 0; c < 4; c++) {
        ushort4 q4 = make_ushort4(f2bf(s[c][0]), f2bf(s[c][1]), f2bf(s[c][2]), f2bf(s[c][3]));
        int blk8 = (c * 4 + lg) ^ ((lr & 7) << 1);
        *(ushort4*)&Ps[w][lr * 64 + blk8 * 4] = q4;
      }
      // rescale O (rows q = lg*4+r) by corr broadcast from lane lg*4+r
      float cr0 = __shfl(corr, lg * 4 + 0, 64);
      float cr1 = __shfl(corr, lg * 4 + 1, 64);
      float cr2 = __shfl(corr, lg * 4 + 2, 64);
      float cr3 = __shfl(corr, lg * 4 + 3, 64);
      #pragma unroll
      for (int nd = 0; nd < 8; nd++) {
        oacc[nd][0] *= cr0; oacc[nd][1] *= cr1;
        oacc[nd][2] *= cr2; oacc[nd][3] *= cr3;
      }
      // O += P V  (A = P from Ps, B = V from Vs)
      #pragma unroll
      for (int ks = 0; ks < 2; ks++) {
        bf16x8 pf = *(const bf16x8*)&Ps[w][lr * 64 +
                     (((2 * (ks * 4 + lg)) ^ ((lr & 7) << 1)) << 2)];
        #pragma unroll
        for (int nd = 0; nd < 8; nd++) {
          const int d = nd * 16 + lr;
          bf16x8 vf = *(const bf16x8*)&Vc[d * 64 + (((ks * 4 + lg) ^ (d & 7)) << 3)];
          oacc[nd] = __builtin_amdgcn_mfma_f32_16x16x32_bf16(pf, vf, oacc[nd], 0, 0, 0);
        }
      }
      asm volatile("s_waitcnt vmcnt(0)" ::: "memory");
      __builtin_amdgcn_s_barrier();
      asm volatile("" ::: "memory");
      cur ^= 1;
    }
    // epilogue
    float inv = 1.0f / lrun;
    float iv0 = __shfl(inv, lg * 4 + 0, 64);
    float iv1 = __shfl(inv, lg * 4 + 1, 64);
    float iv2 = __shfl(inv, lg * 4 + 2, 64);
    float iv3 = __shfl(inv, lg * 4 + 3, 64);
    float iv[4] = {iv0, iv1, iv2, iv3};
    #pragma unroll
    for (int r = 0; r < 4; r++) {
      int orow = q0 + w * 16 + lg * 4 + r;
      size_t base = (size_t)(b * T_ + orow) * 2048 + (size_t)(g * 4 + h) * 128;
      #pragma unroll
      for (int nd = 0; nd < 8; nd++)
        ob[base + nd * 16 + lr] = f2bf(oacc[nd][r] * iv[r]);
    }
  }
}

// ---------- workspace layout (bytes) ----------
#define OFF_XB   ((size_t)0)          /* 16MB */
#define OFF_WQT  ((size_t)16777216)   /*  8MB */
#define OFF_WKVT ((size_t)25165824)   /*  4MB */
#define OFF_WOT  ((size_t)29360128)   /*  8MB */
#define OFF_ROPE ((size_t)37748736)   /*  1MB */
#define OFF_QB   ((size_t)38797312)   /* 16MB */
#define OFF_KB   ((size_t)55574528)   /*  4MB */
#define OFF_VTB  ((size_t)59768832)   /*  4MB */
#define OFF_QF   ((size_t)63963136)   /* 16MB */
#define OFF_KVF  ((size_t)80740352)   /*  8MB */
#define OFF_OB   OFF_QF   /* reuse: q_bf dead once norm_rope_q has run */

extern "C" void kernel_launch(void* const* d_in, const int* in_sizes, int n_in,
                              void* d_out, int out_size, void* d_ws, size_t ws_size,
                              hipStream_t stream) {
  const float* x  = (const float*)d_in[0];
  const float* wq = (const float*)d_in[1];
  const float* wk = (const float*)d_in[2];
  const float* wv = (const float*)d_in[3];
  const float* wo = (const float*)d_in[4];
  const float* gq = (const float*)d_in[5];
  const float* gk = (const float*)d_in[6];
  float* out = (float*)d_out;
  char* ws = (char*)d_ws;

  u16*    xb   = (u16*)(ws + OFF_XB);
  u16*    wqt  = (u16*)(ws + OFF_WQT);
  u16*    wkvt = (u16*)(ws + OFF_WKVT);
  u16*    wot  = (u16*)(ws + OFF_WOT);
  float2* rope = (float2*)(ws + OFF_ROPE);
  u16*    qbuf = (u16*)(ws + OFF_QB);
  u16*    kbuf = (u16*)(ws + OFF_KB);
  u16*    vtb  = (u16*)(ws + OFF_VTB);
  u16*    q_bf = (u16*)(ws + OFF_QF);
  u16*    kv_bf= (u16*)(ws + OFF_KVF);
  u16*    obuf = (u16*)(ws + OFF_OB);

  // 1. conversions
  k_convert<<<8192, 256, 0, stream>>>(x, xb, (MROWS * DM) / 4);
  k_transpose<<<dim3(64, 64), dim3(32, 8), 0, stream>>>(wq, wqt, 2048, 2048);
  k_transpose<<<dim3(16, 64), dim3(32, 8), 0, stream>>>(wk, wkvt, 2048, 512);
  k_transpose<<<dim3(16, 64), dim3(32, 8), 0, stream>>>(wv, wkvt + (size_t)512 * 2048, 2048, 512);
  k_transpose<<<dim3(64, 64), dim3(32, 8), 0, stream>>>(wo, wot, 2048, 2048);
  k_rope_table<<<512, 256, 0, stream>>>(rope);
  // 2. projections (bf16 out); K & V merged into one N=1024 GEMM
  k_gemm<u16><<<dim3(16, 32), 256, 0, stream>>>(xb, wqt, q_bf, MROWS, 2048, 2048);
  k_gemm<u16><<<dim3(8, 32), 256, 0, stream>>>(xb, wkvt, kv_bf, MROWS, 1024, 2048);
  // 3. norm + rope + layout
  k_norm_rope_q<<<16384, 256, 0, stream>>>(q_bf, gq, rope, qbuf);
  k_norm_rope_k<<<4096, 256, 0, stream>>>(kv_bf, gk, rope, kbuf);
  k_pack_vt<<<1024, 256, 0, stream>>>(kv_bf, vtb);
  // 4. attention: paired Q-tiles (31-p then p), uniform work per block
  k_attn<<<dim3(16, 32), 256, 0, stream>>>(qbuf, kbuf, vtb, obuf);
  // 5. output projection (fp32 out)
  k_gemm<float><<<dim3(16, 32), 256, 0, stream>>>(obuf, wot, out, MROWS, 2048, 2048);
}